// Round 8
// baseline (364.150 us; speedup 1.0000x reference)
//
#include <hip/hip_runtime.h>
#include <hip/hip_bf16.h>

// Problem constants
#define B_  32
#define NI_ 1024
#define NT_ 512
#define D_  1024

typedef __attribute__((ext_vector_type(8))) short bf16x8;   // 8 bf16 = 4 VGPRs
typedef __attribute__((ext_vector_type(4))) float f32x4;    // MFMA accumulator

// round-to-nearest-even f32 -> bf16 (values are finite here)
__device__ __forceinline__ ushort f2b(float f) {
  unsigned u = __builtin_bit_cast(unsigned, f);
  u = (u + 0x7FFFu + ((u >> 16) & 1u)) >> 16;
  return (ushort)u;
}

// async global->LDS 16B copy: per-lane global address, LDS dest is
// wave-uniform base + lane*16.
__device__ __forceinline__ void gll16(const ushort* g, ushort* l) {
  __builtin_amdgcn_global_load_lds(
      (const __attribute__((address_space(1))) void*)g,
      (__attribute__((address_space(3))) void*)l, 16, 0, 0);
}

#define VMWAIT(N) asm volatile("s_waitcnt vmcnt(" #N ")" ::: "memory")

// ---------------------------------------------------------------------------
// LayerNorm over D=1024, fp32 in -> bf16 out. One wave per row, 4 rows/block.
// ---------------------------------------------------------------------------
__global__ __launch_bounds__(256) void ln_bf16_kernel(
    const float* __restrict__ x, const float* __restrict__ gamma,
    const float* __restrict__ beta, ushort* __restrict__ out)
{
  const int row  = blockIdx.x * 4 + (threadIdx.x >> 6);
  const int lane = threadIdx.x & 63;
  const float* xr = x + (size_t)row * D_;
  float4 v[4];
  float s = 0.f, sq = 0.f;
#pragma unroll
  for (int q = 0; q < 4; ++q) {
    v[q] = *reinterpret_cast<const float4*>(xr + q * 256 + lane * 4);
    s  += v[q].x + v[q].y + v[q].z + v[q].w;
    sq += v[q].x*v[q].x + v[q].y*v[q].y + v[q].z*v[q].z + v[q].w*v[q].w;
  }
#pragma unroll
  for (int m = 1; m < 64; m <<= 1) {
    s  += __shfl_xor(s,  m);
    sq += __shfl_xor(sq, m);
  }
  const float mean = s * (1.f / D_);
  const float rstd = rsqrtf(sq * (1.f / D_) - mean * mean + 1e-5f);
  ushort* orow = out + (size_t)row * D_;
#pragma unroll
  for (int q = 0; q < 4; ++q) {
    const float4 g  = *reinterpret_cast<const float4*>(gamma + q * 256 + lane * 4);
    const float4 bt = *reinterpret_cast<const float4*>(beta  + q * 256 + lane * 4);
    ushort4 o;
    o.x = f2b((v[q].x - mean) * rstd * g.x + bt.x);
    o.y = f2b((v[q].y - mean) * rstd * g.y + bt.y);
    o.z = f2b((v[q].z - mean) * rstd * g.z + bt.z);
    o.w = f2b((v[q].w - mean) * rstd * g.w + bt.w);
    *reinterpret_cast<ushort4*>(orow + q * 256 + lane * 4) = o;
  }
}

// ---------------------------------------------------------------------------
// bf16 transpose [R][C] -> [C][R], per batch. 64x64 LDS tile.
// grid (C/64, R/64, B), block 256.
// ---------------------------------------------------------------------------
__global__ __launch_bounds__(256) void transpose_bf16_kernel(
    const ushort* __restrict__ in, ushort* __restrict__ out, int R, int C)
{
  __shared__ ushort lds[64][68];
  const size_t nb = (size_t)blockIdx.z * (size_t)R * C;
  const ushort* ib = in + nb;
  ushort* ob = out + nb;
  const int c0 = blockIdx.x * 64, r0 = blockIdx.y * 64;
  const int t = threadIdx.x;
#pragma unroll
  for (int it = 0; it < 2; ++it) {
    const int r = (t >> 3) + 32 * it;
    const int c = (t & 7) * 8;
    uint4 val = *reinterpret_cast<const uint4*>(ib + (size_t)(r0 + r) * C + c0 + c);
    *reinterpret_cast<uint2*>(&lds[r][c])     = make_uint2(val.x, val.y);
    *reinterpret_cast<uint2*>(&lds[r][c + 4]) = make_uint2(val.z, val.w);
  }
  __syncthreads();
#pragma unroll
  for (int it = 0; it < 2; ++it) {
    const int c  = (t >> 3) + 32 * it;  // output row = original col
    const int rb = (t & 7) * 8;         // original row chunk
    union { ushort u[8]; uint4 v; } pk;
#pragma unroll
    for (int j = 0; j < 8; ++j) pk.u[j] = lds[rb + j][c];
    *reinterpret_cast<uint4*>(ob + (size_t)(c0 + c) * R + r0 + rb) = pk.v;
  }
}

// ---------------------------------------------------------------------------
// qk_softmax v7 (FROZEN from R7): reg-staged double-buffer, XOR-swizzled LDS.
// Block = 64 i x 512 t, 8 waves (each 64i x 64t). Grid 512, XCD-swizzled.
// ---------------------------------------------------------------------------
__global__ __launch_bounds__(512) void qk_softmax_kernel(
    const ushort* __restrict__ qn,   // [B][NI][D] bf16
    const ushort* __restrict__ kn,   // [B][NT][D] bf16
    ushort* __restrict__ attn_it,    // [B][NI][NT] bf16
    ushort* __restrict__ attn_ti)    // [B][NT][NI] bf16
{
  __shared__ __align__(16) ushort Asm[2][64 * 32];     // 2 x 4KB
  __shared__ __align__(16) ushort Bsm[2][512 * 32];    // 2 x 32KB
  __shared__ __align__(16) float redm[64][8];
  __shared__ __align__(16) float reds[64][8];

  const int bid = blockIdx.x;
  const int sid = (bid & 7) * 64 + (bid >> 3);
  const int b   = sid >> 4;            // batch
  const int i0  = (sid & 15) * 64;     // i-block base
  const int tid  = threadIdx.x;
  const int w    = tid >> 6;           // wave 0..7 -> t-range w*64
  const int lane = tid & 63;
  const int lr   = lane & 15;
  const int g    = lane >> 4;

  const ushort* qb = qn + ((size_t)b * NI_ + i0) * D_;
  const ushort* kb = kn + (size_t)b * NT_ * D_;

  const int srow = tid >> 2;
  const int scol = (tid & 3) * 8;
  const int wp = (((tid >> 6) << 6) | (((tid >> 2) & 15) << 2)
                | ((tid & 3) ^ ((tid >> 3) & 3))) * 8;
  const int chunkLane = ((lane & 15) << 2) | ((lane >> 4) ^ ((lane >> 1) & 3));

  uint4 ra, rb0, rb1, rb2, rb3;
  auto LOAD = [&](int t) {
    const int ko = t * 32 + scol;
    if (tid < 256) ra = *reinterpret_cast<const uint4*>(qb + (size_t)srow * D_ + ko);
    rb0 = *reinterpret_cast<const uint4*>(kb + (size_t)(srow      ) * D_ + ko);
    rb1 = *reinterpret_cast<const uint4*>(kb + (size_t)(srow + 128) * D_ + ko);
    rb2 = *reinterpret_cast<const uint4*>(kb + (size_t)(srow + 256) * D_ + ko);
    rb3 = *reinterpret_cast<const uint4*>(kb + (size_t)(srow + 384) * D_ + ko);
  };
  auto WRITE = [&](int nb) {
    if (tid < 256) *reinterpret_cast<uint4*>(&Asm[nb][wp]) = ra;
    *reinterpret_cast<uint4*>(&Bsm[nb][wp        ]) = rb0;
    *reinterpret_cast<uint4*>(&Bsm[nb][wp +  4096]) = rb1;
    *reinterpret_cast<uint4*>(&Bsm[nb][wp +  8192]) = rb2;
    *reinterpret_cast<uint4*>(&Bsm[nb][wp + 12288]) = rb3;
  };

  f32x4 acc[4][4];
#pragma unroll
  for (int i = 0; i < 4; ++i)
#pragma unroll
    for (int j = 0; j < 4; ++j) acc[i][j] = (f32x4){0.f, 0.f, 0.f, 0.f};

  LOAD(0); WRITE(0); __syncthreads();
  const int nst = D_ / 32;   // 32
  int cur = 0;
  for (int t = 0; t < nst; ++t) {
    if (t + 1 < nst) LOAD(t + 1);
    const ushort* As = Asm[cur];
    const ushort* Bs = Bsm[cur];
    bf16x8 af[4], bf[4];
#pragma unroll
    for (int i = 0; i < 4; ++i)
      af[i] = *reinterpret_cast<const bf16x8*>(As + (i * 64 + chunkLane) * 8);
#pragma unroll
    for (int j = 0; j < 4; ++j)
      bf[j] = *reinterpret_cast<const bf16x8*>(Bs + ((w * 4 + j) * 64 + chunkLane) * 8);
#pragma unroll
    for (int i = 0; i < 4; ++i)
#pragma unroll
      for (int j = 0; j < 4; ++j)
        acc[i][j] = __builtin_amdgcn_mfma_f32_16x16x32_bf16(af[i], bf[j], acc[i][j], 0, 0, 0);
    __syncthreads();
    if (t + 1 < nst) WRITE(cur ^ 1);
    __syncthreads();
    cur ^= 1;
  }

  // ---- softmax over full t (512) per i-row ----
  const float c1 = 0.03125f * 1.44269504f;  // scale * log2(e)

  float mx[4][4];
#pragma unroll
  for (int i = 0; i < 4; ++i)
#pragma unroll
    for (int r = 0; r < 4; ++r) {
      float m = fmaxf(fmaxf(acc[i][0][r], acc[i][1][r]),
                      fmaxf(acc[i][2][r], acc[i][3][r]));
      m = fmaxf(m, __shfl_xor(m, 1));
      m = fmaxf(m, __shfl_xor(m, 2));
      m = fmaxf(m, __shfl_xor(m, 4));
      m = fmaxf(m, __shfl_xor(m, 8));
      mx[i][r] = m;
    }
  if (lr == 0) {
#pragma unroll
    for (int i = 0; i < 4; ++i)
#pragma unroll
      for (int r = 0; r < 4; ++r) redm[i * 16 + g * 4 + r][w] = mx[i][r];
  }
  __syncthreads();
  float gm[4][4];
#pragma unroll
  for (int i = 0; i < 4; ++i)
#pragma unroll
    for (int r = 0; r < 4; ++r) {
      const int row = i * 16 + g * 4 + r;
      const float4 a0 = *reinterpret_cast<const float4*>(&redm[row][0]);
      const float4 a1 = *reinterpret_cast<const float4*>(&redm[row][4]);
      gm[i][r] = fmaxf(fmaxf(fmaxf(a0.x, a0.y), fmaxf(a0.z, a0.w)),
                       fmaxf(fmaxf(a1.x, a1.y), fmaxf(a1.z, a1.w)));
    }

  float sm[4][4];
#pragma unroll
  for (int i = 0; i < 4; ++i)
#pragma unroll
    for (int r = 0; r < 4; ++r) sm[i][r] = 0.f;
#pragma unroll
  for (int i = 0; i < 4; ++i)
#pragma unroll
    for (int j = 0; j < 4; ++j)
#pragma unroll
      for (int r = 0; r < 4; ++r) {
        const float p = exp2f((acc[i][j][r] - gm[i][r]) * c1);
        acc[i][j][r] = p;
        sm[i][r] += p;
      }
#pragma unroll
  for (int i = 0; i < 4; ++i)
#pragma unroll
    for (int r = 0; r < 4; ++r) {
      float s = sm[i][r];
      s += __shfl_xor(s, 1);
      s += __shfl_xor(s, 2);
      s += __shfl_xor(s, 4);
      s += __shfl_xor(s, 8);
      sm[i][r] = s;
    }
  if (lr == 0) {
#pragma unroll
    for (int i = 0; i < 4; ++i)
#pragma unroll
      for (int r = 0; r < 4; ++r) reds[i * 16 + g * 4 + r][w] = sm[i][r];
  }
  __syncthreads();
  float inv[4][4];
#pragma unroll
  for (int i = 0; i < 4; ++i)
#pragma unroll
    for (int r = 0; r < 4; ++r) {
      const int row = i * 16 + g * 4 + r;
      const float4 a0 = *reinterpret_cast<const float4*>(&reds[row][0]);
      const float4 a1 = *reinterpret_cast<const float4*>(&reds[row][4]);
      inv[i][r] = 1.f / (a0.x + a0.y + a0.z + a0.w + a1.x + a1.y + a1.z + a1.w);
    }

#pragma unroll
  for (int i = 0; i < 4; ++i) {
    const int rbase = i0 + i * 16 + g * 4;
#pragma unroll
    for (int j = 0; j < 4; ++j) {
      const int tcol = w * 64 + j * 16 + lr;
      ushort4 pk;
      pk.x = f2b(acc[i][j][0] * inv[i][0]);
      pk.y = f2b(acc[i][j][1] * inv[i][1]);
      pk.z = f2b(acc[i][j][2] * inv[i][2]);
      pk.w = f2b(acc[i][j][3] * inv[i][3]);
      ushort* it_p = attn_it + ((size_t)b * NI_ + rbase) * NT_ + tcol;
      it_p[0 * NT_] = pk.x;
      it_p[1 * NT_] = pk.y;
      it_p[2 * NT_] = pk.z;
      it_p[3 * NT_] = pk.w;
      *reinterpret_cast<ushort4*>(attn_ti + ((size_t)b * NT_ + tcol) * NI_ + rbase) = pk;
    }
  }
}

// ---------------------------------------------------------------------------
// bt_gemm v7: counted-vmcnt pipeline (T3+T4 mechanism).
// 4 LDS buffers, global_load_lds fragment-order staging (R5 layout,
// correctness-proven, conflict-free reads), 3 tiles in flight, raw s_barrier
// + s_waitcnt vmcnt(8) (never 0 in steady state), sched_barrier fences.
// Race-safety: ISSUE(t+3)->buf[(t-1)&3]; its readers (MFMA(t-1)) are
// separated by the iter-t barrier. Every wave waits its own vmcnt before the
// barrier => tile-t writes globally complete after it.
// BK=32, 128x128 tile, 4 waves 2x2. grid (N/128, M/128, B), block 256.
// ---------------------------------------------------------------------------
__global__ __launch_bounds__(256) void bt_gemm_add_kernel(
    const ushort* __restrict__ A,   // [B][M][K] bf16
    const ushort* __restrict__ Bm,  // [B][N][K] bf16
    const float* __restrict__ add,  // [B][M][N] f32
    float* __restrict__ out,        // [B][M][N] f32
    int M, int N, int K)
{
  __shared__ __align__(16) ushort Asm[4][128 * 32];   // 4 x 8KB
  __shared__ __align__(16) ushort Bsm[4][128 * 32];   // 4 x 8KB

  const int b    = blockIdx.z;
  const int m0   = blockIdx.y * 128;
  const int n0   = blockIdx.x * 128;
  const int tid  = threadIdx.x;
  const int w    = tid >> 6;
  const int lane = tid & 63;
  const int lr   = lane & 15;
  const int g    = lane >> 4;

  const ushort* Ab = A  + ((size_t)b * M + m0) * K;
  const ushort* Bb = Bm + ((size_t)b * N + n0) * K;

  // fragment-order staging: chunk c -> global row ((c>>6)<<4)|(c&15),
  // kcol (c>>4)&3; LDS dest linear (wave-uniform base + lane*16).
  auto ISSUE = [&](int u) {
    const int nb = u & 3;
    const int ko = u * 32;
#pragma unroll
    for (int q = 0; q < 2; ++q) {
      const int c   = q * 256 + tid;
      const int row = ((c >> 6) << 4) | (c & 15);
      const int kc  = (c >> 4) & 3;
      const size_t go = (size_t)row * K + ko + kc * 8;
      const int lbase = (q * 256 + w * 64) * 8;
      gll16(Ab + go, &Asm[nb][lbase]);
      gll16(Bb + go, &Bsm[nb][lbase]);
    }
  };

  f32x4 acc[4][4];
#pragma unroll
  for (int i = 0; i < 4; ++i)
#pragma unroll
    for (int j = 0; j < 4; ++j) acc[i][j] = (f32x4){0.f, 0.f, 0.f, 0.f};

  const int nst = K / 32;   // 16 (gemm5) or 32 (gemm7)
  ISSUE(0); ISSUE(1); ISSUE(2);   // 12 ops/thread in flight

  for (int t = 0; t < nst; ++t) {
    // guarantee tile t's loads complete, keep t+1/t+2 in flight
    if (t + 2 < nst)      VMWAIT(8);
    else if (t + 1 < nst) VMWAIT(4);
    else                  VMWAIT(0);
    __builtin_amdgcn_sched_barrier(0);
    __builtin_amdgcn_s_barrier();
    __builtin_amdgcn_sched_barrier(0);

    const ushort* As = Asm[t & 3];
    const ushort* Bs = Bsm[t & 3];
    bf16x8 af[4], bf[4];
#pragma unroll
    for (int i = 0; i < 4; ++i)
      af[i] = *reinterpret_cast<const bf16x8*>(
          As + (((w >> 1) * 4 + i) * 64 + lane) * 8);
#pragma unroll
    for (int j = 0; j < 4; ++j)
      bf[j] = *reinterpret_cast<const bf16x8*>(
          Bs + (((w & 1) * 4 + j) * 64 + lane) * 8);
#pragma unroll
    for (int i = 0; i < 4; ++i)
#pragma unroll
      for (int j = 0; j < 4; ++j)
        acc[i][j] = __builtin_amdgcn_mfma_f32_16x16x32_bf16(af[i], bf[j], acc[i][j], 0, 0, 0);

    if (t + 3 < nst) ISSUE(t + 3);   // into buf[(t-1)&3]: readers done pre-barrier
  }

  const size_t ob = (size_t)b * M * N;
  const int rbase = m0 + (w >> 1) * 64 + g * 4;
#pragma unroll
  for (int i = 0; i < 4; ++i)
#pragma unroll
    for (int j = 0; j < 4; ++j) {
      const int c = n0 + (w & 1) * 64 + j * 16 + lr;
#pragma unroll
      for (int r = 0; r < 4; ++r) {
        const size_t idx = ob + (size_t)(rbase + i * 16 + r) * N + c;
        out[idx] = add[idx] + acc[i][j][r];
      }
    }
}

// ---------------------------------------------------------------------------
// Schedule (buffer aliasing; ws_size >= 96 MB, observed ~768MB):
//   imn in out1 region, txn in out0 region (dead before outputs written);
//   ws: [attn_ti][attn_it][txnT]; imnT reuses attn_it+txnT after GEMM5.
// ---------------------------------------------------------------------------
extern "C" void kernel_launch(void* const* d_in, const int* in_sizes, int n_in,
                              void* d_out, int out_size, void* d_ws, size_t ws_size,
                              hipStream_t stream) {
  const float* imgf  = (const float*)d_in[0];
  const float* txtf  = (const float*)d_in[1];
  const float* gamma = (const float*)d_in[2];
  const float* beta  = (const float*)d_in[3];

  float* out0 = (float*)d_out;                       // [B][NI][D] f32
  float* out1 = out0 + (size_t)B_ * NI_ * D_;        // [B][NT][D] f32

  const size_t SZ = (size_t)B_ * NT_ * NI_ * 2;      // 33,554,432 B
  char* ws = (char*)d_ws;
  ushort* attn_ti = (ushort*)ws;                     // [B][NT][NI]
  ushort* attn_it = (ushort*)(ws + SZ);              // [B][NI][NT]
  ushort* txnT    = (ushort*)(ws + 2 * SZ);          // [B][D][NT]
  ushort* imnT    = (ushort*)(ws + SZ);              // [B][D][NI] (aliases attn_it+txnT)
  ushort* imn     = (ushort*)out1;                   // [B][NI][D] bf16 (scratch in out1)
  ushort* txn     = (ushort*)out0;                   // [B][NT][D] bf16 (scratch in out0)

  // 1-2: layernorms -> bf16
  ln_bf16_kernel<<<(B_ * NI_) / 4, 256, 0, stream>>>(imgf, gamma, beta, imn);
  ln_bf16_kernel<<<(B_ * NT_) / 4, 256, 0, stream>>>(txtf, gamma, beta, txn);
  // 3: QK^T + softmax -> attn in both layouts (512 blocks, XCD-swizzled)
  qk_softmax_kernel<<<(NI_ / 64) * B_, 512, 0, stream>>>(imn, txn, attn_it, attn_ti);
  // 4: text_norm^T
  transpose_bf16_kernel<<<dim3(D_ / 64, NT_ / 64, B_), 256, 0, stream>>>(txn, txnT, NT_, D_);
  // 5: out0 = image + attn @ text_norm   (overwrites txn scratch — dead)
  bt_gemm_add_kernel<<<dim3(D_ / 128, NI_ / 128, B_), 256, 0, stream>>>(
      attn_it, txnT, imgf, out0, NI_, D_, NT_);
  // 6: image_norm^T (overwrites attn_it + txnT — dead)
  transpose_bf16_kernel<<<dim3(D_ / 64, NI_ / 64, B_), 256, 0, stream>>>(imn, imnT, NI_, D_);
  // 7: out1 = text + attn^T @ image_norm (overwrites imn scratch — dead)
  bt_gemm_add_kernel<<<dim3(D_ / 128, NT_ / 128, B_), 256, 0, stream>>>(
      attn_ti, imnT, txtf, out1, NT_, D_, NI_);
}

// Round 9
// 363.696 us; speedup vs baseline: 1.0012x; 1.0012x over previous
//
#include <hip/hip_runtime.h>
#include <hip/hip_bf16.h>

// Problem constants
#define B_  32
#define NI_ 1024
#define NT_ 512
#define D_  1024

typedef __attribute__((ext_vector_type(8))) short bf16x8;   // 8 bf16 = 4 VGPRs
typedef __attribute__((ext_vector_type(4))) float f32x4;    // MFMA accumulator

// round-to-nearest-even f32 -> bf16 (values are finite here)
__device__ __forceinline__ ushort f2b(float f) {
  unsigned u = __builtin_bit_cast(unsigned, f);
  u = (u + 0x7FFFu + ((u >> 16) & 1u)) >> 16;
  return (ushort)u;
}

// ---------------------------------------------------------------------------
// LayerNorm over D=1024, fp32 in -> bf16 out. One wave per row, 4 rows/block.
// ---------------------------------------------------------------------------
__global__ __launch_bounds__(256) void ln_bf16_kernel(
    const float* __restrict__ x, const float* __restrict__ gamma,
    const float* __restrict__ beta, ushort* __restrict__ out)
{
  const int row  = blockIdx.x * 4 + (threadIdx.x >> 6);
  const int lane = threadIdx.x & 63;
  const float* xr = x + (size_t)row * D_;
  float4 v[4];
  float s = 0.f, sq = 0.f;
#pragma unroll
  for (int q = 0; q < 4; ++q) {
    v[q] = *reinterpret_cast<const float4*>(xr + q * 256 + lane * 4);
    s  += v[q].x + v[q].y + v[q].z + v[q].w;
    sq += v[q].x*v[q].x + v[q].y*v[q].y + v[q].z*v[q].z + v[q].w*v[q].w;
  }
#pragma unroll
  for (int m = 1; m < 64; m <<= 1) {
    s  += __shfl_xor(s,  m);
    sq += __shfl_xor(sq, m);
  }
  const float mean = s * (1.f / D_);
  const float rstd = rsqrtf(sq * (1.f / D_) - mean * mean + 1e-5f);
  ushort* orow = out + (size_t)row * D_;
#pragma unroll
  for (int q = 0; q < 4; ++q) {
    const float4 g  = *reinterpret_cast<const float4*>(gamma + q * 256 + lane * 4);
    const float4 bt = *reinterpret_cast<const float4*>(beta  + q * 256 + lane * 4);
    ushort4 o;
    o.x = f2b((v[q].x - mean) * rstd * g.x + bt.x);
    o.y = f2b((v[q].y - mean) * rstd * g.y + bt.y);
    o.z = f2b((v[q].z - mean) * rstd * g.z + bt.z);
    o.w = f2b((v[q].w - mean) * rstd * g.w + bt.w);
    *reinterpret_cast<ushort4*>(orow + q * 256 + lane * 4) = o;
  }
}

// ---------------------------------------------------------------------------
// bf16 transpose [R][C] -> [C][R], per batch. 64x64 LDS tile.
// grid (C/64, R/64, B), block 256.
// ---------------------------------------------------------------------------
__global__ __launch_bounds__(256) void transpose_bf16_kernel(
    const ushort* __restrict__ in, ushort* __restrict__ out, int R, int C)
{
  __shared__ ushort lds[64][68];
  const size_t nb = (size_t)blockIdx.z * (size_t)R * C;
  const ushort* ib = in + nb;
  ushort* ob = out + nb;
  const int c0 = blockIdx.x * 64, r0 = blockIdx.y * 64;
  const int t = threadIdx.x;
#pragma unroll
  for (int it = 0; it < 2; ++it) {
    const int r = (t >> 3) + 32 * it;
    const int c = (t & 7) * 8;
    uint4 val = *reinterpret_cast<const uint4*>(ib + (size_t)(r0 + r) * C + c0 + c);
    *reinterpret_cast<uint2*>(&lds[r][c])     = make_uint2(val.x, val.y);
    *reinterpret_cast<uint2*>(&lds[r][c + 4]) = make_uint2(val.z, val.w);
  }
  __syncthreads();
#pragma unroll
  for (int it = 0; it < 2; ++it) {
    const int c  = (t >> 3) + 32 * it;  // output row = original col
    const int rb = (t & 7) * 8;         // original row chunk
    union { ushort u[8]; uint4 v; } pk;
#pragma unroll
    for (int j = 0; j < 8; ++j) pk.u[j] = lds[rb + j][c];
    *reinterpret_cast<uint4*>(ob + (size_t)(c0 + c) * R + r0 + rb) = pk.v;
  }
}

// ---------------------------------------------------------------------------
// FUSED qk_softmax + PV + residual epilogue.
// Per block (b, i0): QK^T (R7 structure) -> softmax -> write attn_ti global
// (for the text_attended GEMM) -> write P to LDS (aliases dead QK staging,
// row pad +16B -> <=2-way banks) -> PV: out0 = imgf + P @ txnT^T, A-frags
// from LDS, B-frags from txnT (L2-resident 1MB/batch).
// Eliminates gemm5 + all attn_it traffic (~65MB + a 123us dispatch).
// Block = 64 i x 512 t, 8 waves; PV: wave w owns d-cols [w*128, w*128+128).
// Grid 512, XCD-swizzled.
// ---------------------------------------------------------------------------
__global__ __launch_bounds__(512) void attn_fused_kernel(
    const ushort* __restrict__ qn,   // [B][NI][D] bf16 (image_norm)
    const ushort* __restrict__ kn,   // [B][NT][D] bf16 (text_norm)
    const ushort* __restrict__ vt,   // [B][D][NT] bf16 (text_norm^T)
    const float*  __restrict__ addm, // [B][NI][D] f32  (image residual)
    ushort* __restrict__ attn_ti,    // [B][NT][NI] bf16
    float*  __restrict__ out0)       // [B][NI][D] f32
{
  // 72KB staging arena; P (64 rows x 520 ushorts = 66,560B) aliases it later.
  __shared__ __align__(16) ushort raw[36864];
  __shared__ __align__(16) float redm[64][8];
  __shared__ __align__(16) float reds[64][8];

  const int bid = blockIdx.x;
  const int sid = (bid & 7) * 64 + (bid >> 3);
  const int b   = sid >> 4;            // batch
  const int i0  = (sid & 15) * 64;     // i-block base
  const int tid  = threadIdx.x;
  const int w    = tid >> 6;           // wave 0..7
  const int lane = tid & 63;
  const int lr   = lane & 15;
  const int g    = lane >> 4;

  const ushort* qb = qn + ((size_t)b * NI_ + i0) * D_;
  const ushort* kb = kn + (size_t)b * NT_ * D_;

  const int srow = tid >> 2;
  const int scol = (tid & 3) * 8;
  const int wp = (((tid >> 6) << 6) | (((tid >> 2) & 15) << 2)
                | ((tid & 3) ^ ((tid >> 3) & 3))) * 8;
  const int chunkLane = ((lane & 15) << 2) | ((lane >> 4) ^ ((lane >> 1) & 3));

  uint4 ra, rb0, rb1, rb2, rb3;
  auto LOAD = [&](int t) {
    const int ko = t * 32 + scol;
    if (tid < 256) ra = *reinterpret_cast<const uint4*>(qb + (size_t)srow * D_ + ko);
    rb0 = *reinterpret_cast<const uint4*>(kb + (size_t)(srow      ) * D_ + ko);
    rb1 = *reinterpret_cast<const uint4*>(kb + (size_t)(srow + 128) * D_ + ko);
    rb2 = *reinterpret_cast<const uint4*>(kb + (size_t)(srow + 256) * D_ + ko);
    rb3 = *reinterpret_cast<const uint4*>(kb + (size_t)(srow + 384) * D_ + ko);
  };
  auto WRITE = [&](int nb) {
    ushort* As = raw + nb * 2048;
    ushort* Bs = raw + 4096 + nb * 16384;
    if (tid < 256) *reinterpret_cast<uint4*>(&As[wp]) = ra;
    *reinterpret_cast<uint4*>(&Bs[wp        ]) = rb0;
    *reinterpret_cast<uint4*>(&Bs[wp +  4096]) = rb1;
    *reinterpret_cast<uint4*>(&Bs[wp +  8192]) = rb2;
    *reinterpret_cast<uint4*>(&Bs[wp + 12288]) = rb3;
  };

  f32x4 acc[4][4];
#pragma unroll
  for (int i = 0; i < 4; ++i)
#pragma unroll
    for (int j = 0; j < 4; ++j) acc[i][j] = (f32x4){0.f, 0.f, 0.f, 0.f};

  LOAD(0); WRITE(0); __syncthreads();
  const int nst = D_ / 32;   // 32
  int cur = 0;
  for (int t = 0; t < nst; ++t) {
    if (t + 1 < nst) LOAD(t + 1);
    const ushort* As = raw + cur * 2048;
    const ushort* Bs = raw + 4096 + cur * 16384;
    bf16x8 af[4], bf[4];
#pragma unroll
    for (int i = 0; i < 4; ++i)
      af[i] = *reinterpret_cast<const bf16x8*>(As + (i * 64 + chunkLane) * 8);
#pragma unroll
    for (int j = 0; j < 4; ++j)
      bf[j] = *reinterpret_cast<const bf16x8*>(Bs + ((w * 4 + j) * 64 + chunkLane) * 8);
#pragma unroll
    for (int i = 0; i < 4; ++i)
#pragma unroll
      for (int j = 0; j < 4; ++j)
        acc[i][j] = __builtin_amdgcn_mfma_f32_16x16x32_bf16(af[i], bf[j], acc[i][j], 0, 0, 0);
    __syncthreads();
    if (t + 1 < nst) WRITE(cur ^ 1);
    __syncthreads();
    cur ^= 1;
  }

  // ---- softmax over full t (512) per i-row ----
  // C/D: row(i) = i*16 + g*4 + r, col(t) = w*64 + j*16 + lr
  const float c1 = 0.03125f * 1.44269504f;  // scale * log2(e)

  float mx[4][4];
#pragma unroll
  for (int i = 0; i < 4; ++i)
#pragma unroll
    for (int r = 0; r < 4; ++r) {
      float m = fmaxf(fmaxf(acc[i][0][r], acc[i][1][r]),
                      fmaxf(acc[i][2][r], acc[i][3][r]));
      m = fmaxf(m, __shfl_xor(m, 1));
      m = fmaxf(m, __shfl_xor(m, 2));
      m = fmaxf(m, __shfl_xor(m, 4));
      m = fmaxf(m, __shfl_xor(m, 8));
      mx[i][r] = m;
    }
  if (lr == 0) {
#pragma unroll
    for (int i = 0; i < 4; ++i)
#pragma unroll
      for (int r = 0; r < 4; ++r) redm[i * 16 + g * 4 + r][w] = mx[i][r];
  }
  __syncthreads();
  float gm[4][4];
#pragma unroll
  for (int i = 0; i < 4; ++i)
#pragma unroll
    for (int r = 0; r < 4; ++r) {
      const int row = i * 16 + g * 4 + r;
      const float4 a0 = *reinterpret_cast<const float4*>(&redm[row][0]);
      const float4 a1 = *reinterpret_cast<const float4*>(&redm[row][4]);
      gm[i][r] = fmaxf(fmaxf(fmaxf(a0.x, a0.y), fmaxf(a0.z, a0.w)),
                       fmaxf(fmaxf(a1.x, a1.y), fmaxf(a1.z, a1.w)));
    }

  float sm[4][4];
#pragma unroll
  for (int i = 0; i < 4; ++i)
#pragma unroll
    for (int r = 0; r < 4; ++r) sm[i][r] = 0.f;
#pragma unroll
  for (int i = 0; i < 4; ++i)
#pragma unroll
    for (int j = 0; j < 4; ++j)
#pragma unroll
      for (int r = 0; r < 4; ++r) {
        const float p = exp2f((acc[i][j][r] - gm[i][r]) * c1);
        acc[i][j][r] = p;
        sm[i][r] += p;
      }
#pragma unroll
  for (int i = 0; i < 4; ++i)
#pragma unroll
    for (int r = 0; r < 4; ++r) {
      float s = sm[i][r];
      s += __shfl_xor(s, 1);
      s += __shfl_xor(s, 2);
      s += __shfl_xor(s, 4);
      s += __shfl_xor(s, 8);
      sm[i][r] = s;
    }
  if (lr == 0) {
#pragma unroll
    for (int i = 0; i < 4; ++i)
#pragma unroll
      for (int r = 0; r < 4; ++r) reds[i * 16 + g * 4 + r][w] = sm[i][r];
  }
  __syncthreads();
  float inv[4][4];
#pragma unroll
  for (int i = 0; i < 4; ++i)
#pragma unroll
    for (int r = 0; r < 4; ++r) {
      const int row = i * 16 + g * 4 + r;
      const float4 a0 = *reinterpret_cast<const float4*>(&reds[row][0]);
      const float4 a1 = *reinterpret_cast<const float4*>(&reds[row][4]);
      inv[i][r] = 1.f / (a0.x + a0.y + a0.z + a0.w + a1.x + a1.y + a1.z + a1.w);
    }

  // ---- write attn_ti (global) + P (LDS, row stride 520 ushorts) ----
  // raw's QK buffers are dead (last MFMA read was before the loop-final
  // barrier); softmax touched only redm/reds. One more barrier below before
  // PV reads P.
  ushort* P = raw;
#pragma unroll
  for (int i = 0; i < 4; ++i) {
    const int rbase = i0 + i * 16 + g * 4;
#pragma unroll
    for (int j = 0; j < 4; ++j) {
      const int tcol = w * 64 + j * 16 + lr;
      ushort4 pk;
      pk.x = f2b(acc[i][j][0] * inv[i][0]);
      pk.y = f2b(acc[i][j][1] * inv[i][1]);
      pk.z = f2b(acc[i][j][2] * inv[i][2]);
      pk.w = f2b(acc[i][j][3] * inv[i][3]);
      *reinterpret_cast<ushort4*>(attn_ti + ((size_t)b * NT_ + tcol) * NI_ + rbase) = pk;
      const int prow = i * 16 + g * 4;
      P[(prow + 0) * 520 + tcol] = pk.x;
      P[(prow + 1) * 520 + tcol] = pk.y;
      P[(prow + 2) * 520 + tcol] = pk.z;
      P[(prow + 3) * 520 + tcol] = pk.w;
    }
  }
  __syncthreads();

  // ---- PV: out-tile 64 i x 1024 d; wave w owns d in [w*128, w*128+128) ----
  f32x4 apv[4][8];
#pragma unroll
  for (int i = 0; i < 4; ++i)
#pragma unroll
    for (int n = 0; n < 8; ++n) apv[i][n] = (f32x4){0.f, 0.f, 0.f, 0.f};

  const ushort* vb = vt + (size_t)b * D_ * NT_;   // [d][t]
#pragma unroll 1
  for (int ts = 0; ts < NT_ / 32; ++ts) {         // 16 k-steps over t
    bf16x8 paf[4], pbf[8];
#pragma unroll
    for (int i = 0; i < 4; ++i)
      paf[i] = *reinterpret_cast<const bf16x8*>(P + (i * 16 + lr) * 520 + ts * 32 + g * 8);
#pragma unroll
    for (int n = 0; n < 8; ++n)
      pbf[n] = *reinterpret_cast<const bf16x8*>(
          vb + (size_t)(w * 128 + n * 16 + lr) * NT_ + ts * 32 + g * 8);
#pragma unroll
    for (int i = 0; i < 4; ++i)
#pragma unroll
      for (int n = 0; n < 8; ++n)
        apv[i][n] = __builtin_amdgcn_mfma_f32_16x16x32_bf16(paf[i], pbf[n], apv[i][n], 0, 0, 0);
  }

  // ---- epilogue: out0 = imgf + PV ----
  const float* addb = addm + ((size_t)b * NI_ + i0) * D_;
  float* outb = out0 + ((size_t)b * NI_ + i0) * D_;
#pragma unroll
  for (int i = 0; i < 4; ++i)
#pragma unroll
    for (int n = 0; n < 8; ++n) {
      const int col = w * 128 + n * 16 + lr;
#pragma unroll
      for (int r = 0; r < 4; ++r) {
        const int idx = (i * 16 + g * 4 + r) * D_ + col;
        outb[idx] = addb[idx] + apv[i][n][r];
      }
    }
}

// ---------------------------------------------------------------------------
// bt_gemm (R7 version, reverted): reg-staged double-buffer, XOR-swizzled LDS.
// C[m][n] = add[m][n] + sum_k A[m][k]*Bm[n][k]. BK=32, 128x128 tile, 4 waves.
// grid (N/128, M/128, B), block 256. Used only for text_attended now.
// ---------------------------------------------------------------------------
__global__ __launch_bounds__(256) void bt_gemm_add_kernel(
    const ushort* __restrict__ A,   // [B][M][K] bf16
    const ushort* __restrict__ Bm,  // [B][N][K] bf16
    const float* __restrict__ add,  // [B][M][N] f32
    float* __restrict__ out,        // [B][M][N] f32
    int M, int N, int K)
{
  __shared__ __align__(16) ushort Asm[2][128 * 32];   // 2 x 8KB
  __shared__ __align__(16) ushort Bsm[2][128 * 32];   // 2 x 8KB

  const int b    = blockIdx.z;
  const int m0   = blockIdx.y * 128;
  const int n0   = blockIdx.x * 128;
  const int tid  = threadIdx.x;
  const int w    = tid >> 6;
  const int lane = tid & 63;
  const int lr   = lane & 15;
  const int g    = lane >> 4;

  const ushort* Ab = A  + ((size_t)b * M + m0) * K;
  const ushort* Bb = Bm + ((size_t)b * N + n0) * K;

  const int srow = tid >> 2;           // 0..63
  const int scol = (tid & 3) * 8;
  const int wp = (((tid >> 6) << 6) | (((tid >> 2) & 15) << 2)
                | ((tid & 3) ^ ((tid >> 3) & 3))) * 8;
  const int chunkLane = ((lane & 15) << 2) | ((lane >> 4) ^ ((lane >> 1) & 3));

  uint4 ra0, ra1, rbx0, rbx1;
  auto LOAD = [&](int t) {
    const int ko = t * 32 + scol;
    ra0  = *reinterpret_cast<const uint4*>(Ab + (size_t)(srow     ) * K + ko);
    ra1  = *reinterpret_cast<const uint4*>(Ab + (size_t)(srow + 64) * K + ko);
    rbx0 = *reinterpret_cast<const uint4*>(Bb + (size_t)(srow     ) * K + ko);
    rbx1 = *reinterpret_cast<const uint4*>(Bb + (size_t)(srow + 64) * K + ko);
  };
  auto WRITE = [&](int nb) {
    *reinterpret_cast<uint4*>(&Asm[nb][wp       ]) = ra0;
    *reinterpret_cast<uint4*>(&Asm[nb][wp + 2048]) = ra1;
    *reinterpret_cast<uint4*>(&Bsm[nb][wp       ]) = rbx0;
    *reinterpret_cast<uint4*>(&Bsm[nb][wp + 2048]) = rbx1;
  };

  f32x4 acc[4][4];
#pragma unroll
  for (int i = 0; i < 4; ++i)
#pragma unroll
    for (int j = 0; j < 4; ++j) acc[i][j] = (f32x4){0.f, 0.f, 0.f, 0.f};

  LOAD(0); WRITE(0); __syncthreads();
  const int nst = K / 32;
  int cur = 0;
  for (int t = 0; t < nst; ++t) {
    if (t + 1 < nst) LOAD(t + 1);
    const ushort* As = Asm[cur];
    const ushort* Bs = Bsm[cur];
    bf16x8 af[4], bf[4];
#pragma unroll
    for (int i = 0; i < 4; ++i)
      af[i] = *reinterpret_cast<const bf16x8*>(
          As + (((w >> 1) * 4 + i) * 64 + chunkLane) * 8);
#pragma unroll
    for (int j = 0; j < 4; ++j)
      bf[j] = *reinterpret_cast<const bf16x8*>(
          Bs + (((w & 1) * 4 + j) * 64 + chunkLane) * 8);
#pragma unroll
    for (int i = 0; i < 4; ++i)
#pragma unroll
      for (int j = 0; j < 4; ++j)
        acc[i][j] = __builtin_amdgcn_mfma_f32_16x16x32_bf16(af[i], bf[j], acc[i][j], 0, 0, 0);
    __syncthreads();
    if (t + 1 < nst) WRITE(cur ^ 1);
    __syncthreads();
    cur ^= 1;
  }

  const size_t ob = (size_t)b * M * N;
  const int rbase = m0 + (w >> 1) * 64 + g * 4;
#pragma unroll
  for (int i = 0; i < 4; ++i)
#pragma unroll
    for (int j = 0; j < 4; ++j) {
      const int c = n0 + (w & 1) * 64 + j * 16 + lr;
#pragma unroll
      for (int r = 0; r < 4; ++r) {
        const size_t idx = ob + (size_t)(rbase + i * 16 + r) * N + c;
        out[idx] = add[idx] + acc[i][j][r];
      }
    }
}

// ---------------------------------------------------------------------------
// Schedule (all intermediates in ws; 224MB <= observed ~768MB, no aliasing):
//   ws: [attn_ti 32MB][txnT 32MB][imnT 64MB][txn 32MB][imn 64MB]
//   1. ln(imgf)->imn   2. ln(txtf)->txn   3. transpose txn->txnT
//   4. fused(imn,txn,txnT,imgf)->attn_ti,out0   5. transpose imn->imnT
//   6. bt_gemm(attn_ti,imnT,txtf)->out1
// ---------------------------------------------------------------------------
extern "C" void kernel_launch(void* const* d_in, const int* in_sizes, int n_in,
                              void* d_out, int out_size, void* d_ws, size_t ws_size,
                              hipStream_t stream) {
  const float* imgf  = (const float*)d_in[0];
  const float* txtf  = (const float*)d_in[1];
  const float* gamma = (const float*)d_in[2];
  const float* beta  = (const float*)d_in[3];

  float* out0 = (float*)d_out;                       // [B][NI][D] f32
  float* out1 = out0 + (size_t)B_ * NI_ * D_;        // [B][NT][D] f32

  const size_t MB32 = (size_t)B_ * NT_ * NI_ * 2;    // 33,554,432 B
  char* ws = (char*)d_ws;
  ushort* attn_ti = (ushort*)ws;                     // [B][NT][NI]  32MB
  ushort* txnT    = (ushort*)(ws +     MB32);        // [B][D][NT]   32MB
  ushort* imnT    = (ushort*)(ws + 2 * MB32);        // [B][D][NI]   64MB
  ushort* txn     = (ushort*)(ws + 4 * MB32);        // [B][NT][D]   32MB
  ushort* imn     = (ushort*)(ws + 5 * MB32);        // [B][NI][D]   64MB

  // 1-2: layernorms -> bf16
  ln_bf16_kernel<<<(B_ * NI_) / 4, 256, 0, stream>>>(imgf, gamma, beta, imn);
  ln_bf16_kernel<<<(B_ * NT_) / 4, 256, 0, stream>>>(txtf, gamma, beta, txn);
  // 3: text_norm^T (needed by fused PV)
  transpose_bf16_kernel<<<dim3(D_ / 64, NT_ / 64, B_), 256, 0, stream>>>(txn, txnT, NT_, D_);
  // 4: fused QK^T + softmax + PV + residual -> out0 (and attn_ti for step 6)
  attn_fused_kernel<<<(NI_ / 64) * B_, 512, 0, stream>>>(
      imn, txn, txnT, imgf, attn_ti, out0);
  // 5: image_norm^T
  transpose_bf16_kernel<<<dim3(D_ / 64, NI_ / 64, B_), 256, 0, stream>>>(imn, imnT, NI_, D_);
  // 6: out1 = text + attn^T @ image_norm
  bt_gemm_add_kernel<<<dim3(D_ / 128, NT_ / 128, B_), 256, 0, stream>>>(
      attn_ti, imnT, txtf, out1, NT_, D_, NI_);
}

// Round 10
// 359.236 us; speedup vs baseline: 1.0137x; 1.0124x over previous
//
#include <hip/hip_runtime.h>
#include <hip/hip_bf16.h>

// Problem constants
#define B_  32
#define NI_ 1024
#define NT_ 512
#define D_  1024

typedef __attribute__((ext_vector_type(8))) short bf16x8;   // 8 bf16 = 4 VGPRs
typedef __attribute__((ext_vector_type(4))) float f32x4;    // MFMA accumulator

// round-to-nearest-even f32 -> bf16 (values are finite here)
__device__ __forceinline__ ushort f2b(float f) {
  unsigned u = __builtin_bit_cast(unsigned, f);
  u = (u + 0x7FFFu + ((u >> 16) & 1u)) >> 16;
  return (ushort)u;
}

// ---------------------------------------------------------------------------
// PANEL layout (R10): GEMM operands are pre-packed by their producers into
// fragment-order tiles so the GEMM staging reads are fully SEQUENTIAL
// (theory: 64B-granule scattered first-touch caps HBM at ~3 TB/s; streaming
// hits ~7 TB/s — fill/LN evidence).
//   Panel = [batch][mt = Mdim/128][ks = K/32] tiles of 4096 ushorts.
//   Tile chunk c (of 512, 8 ushorts each): row R = ((c>>6)<<4)|(c&15),
//   kc = (c>>4)&3  (k-cols kc*8..+7). Element (R, k): c = ((R>>4)<<6) |
//   (((k>>3)&3)<<4) | (R&15), ushort offset c*8 + (k&7).
//   MFMA A/B frag for lane l, 16-row block bi = chunk bi*64 + l  -> lane-
//   linear ds_read_b128, conflict-free (verified R5: 262K ~ 0).
// ---------------------------------------------------------------------------

// ---------------------------------------------------------------------------
// LayerNorm over D=1024, fp32 in -> bf16 out. One wave per row, 4 rows/block.
// ---------------------------------------------------------------------------
__global__ __launch_bounds__(256) void ln_bf16_kernel(
    const float* __restrict__ x, const float* __restrict__ gamma,
    const float* __restrict__ beta, ushort* __restrict__ out)
{
  const int row  = blockIdx.x * 4 + (threadIdx.x >> 6);
  const int lane = threadIdx.x & 63;
  const float* xr = x + (size_t)row * D_;
  float4 v[4];
  float s = 0.f, sq = 0.f;
#pragma unroll
  for (int q = 0; q < 4; ++q) {
    v[q] = *reinterpret_cast<const float4*>(xr + q * 256 + lane * 4);
    s  += v[q].x + v[q].y + v[q].z + v[q].w;
    sq += v[q].x*v[q].x + v[q].y*v[q].y + v[q].z*v[q].z + v[q].w*v[q].w;
  }
#pragma unroll
  for (int m = 1; m < 64; m <<= 1) {
    s  += __shfl_xor(s,  m);
    sq += __shfl_xor(sq, m);
  }
  const float mean = s * (1.f / D_);
  const float rstd = rsqrtf(sq * (1.f / D_) - mean * mean + 1e-5f);
  ushort* orow = out + (size_t)row * D_;
#pragma unroll
  for (int q = 0; q < 4; ++q) {
    const float4 g  = *reinterpret_cast<const float4*>(gamma + q * 256 + lane * 4);
    const float4 bt = *reinterpret_cast<const float4*>(beta  + q * 256 + lane * 4);
    ushort4 o;
    o.x = f2b((v[q].x - mean) * rstd * g.x + bt.x);
    o.y = f2b((v[q].y - mean) * rstd * g.y + bt.y);
    o.z = f2b((v[q].z - mean) * rstd * g.z + bt.z);
    o.w = f2b((v[q].w - mean) * rstd * g.w + bt.w);
    *reinterpret_cast<ushort4*>(orow + q * 256 + lane * 4) = o;
  }
}

// ---------------------------------------------------------------------------
// bf16 transpose [R][C] row-major -> B-operand PANELS (N-dim rows = C,
// k-dim = R). 64x64 LDS tile. Writes one full 16B chunk per output store.
// grid (C/64, R/64, B), block 256.
// ---------------------------------------------------------------------------
__global__ __launch_bounds__(256) void transpose_pan_kernel(
    const ushort* __restrict__ in, ushort* __restrict__ outp, int R, int C)
{
  __shared__ ushort lds[64][68];
  const ushort* ib = in + (size_t)blockIdx.z * (size_t)R * C;
  const int c0 = blockIdx.x * 64, r0 = blockIdx.y * 64;
  const int t = threadIdx.x;
  const int nMT = C >> 7, nKS = R >> 5;
#pragma unroll
  for (int it = 0; it < 2; ++it) {
    const int r = (t >> 3) + 32 * it;
    const int c = (t & 7) * 8;
    uint4 val = *reinterpret_cast<const uint4*>(ib + (size_t)(r0 + r) * C + c0 + c);
    *reinterpret_cast<uint2*>(&lds[r][c])     = make_uint2(val.x, val.y);
    *reinterpret_cast<uint2*>(&lds[r][c + 4]) = make_uint2(val.z, val.w);
  }
  __syncthreads();
#pragma unroll
  for (int it = 0; it < 2; ++it) {
    const int c  = (t >> 3) + 32 * it;  // output N-row = original col
    const int rb = (t & 7) * 8;         // k base (8-run, 8-aligned)
    union { ushort u[8]; uint4 v; } pk;
#pragma unroll
    for (int j = 0; j < 8; ++j) pk.u[j] = lds[rb + j][c];
    const int n  = c0 + c;
    const int kb = r0 + rb;
    const size_t tb = ((size_t)blockIdx.z * nMT + (n >> 7)) * nKS + (kb >> 5);
    const int ch = (((n & 127) >> 4) << 6) | (((kb >> 3) & 3) << 4) | (n & 15);
    *reinterpret_cast<uint4*>(outp + tb * 4096 + ch * 8) = pk.v;
  }
}

// ---------------------------------------------------------------------------
// qk_softmax v8: R7 structure (reg-staged dbuf, XOR-swizzled LDS) unchanged;
// epilogue now writes attn in BOTH GEMMs' A-PANEL layouts.
// Block = 64 i x 512 t, 8 waves. Grid 512, XCD-swizzled.
// ---------------------------------------------------------------------------
__global__ __launch_bounds__(512) void qk_softmax_kernel(
    const ushort* __restrict__ qn,   // [B][NI][D] bf16
    const ushort* __restrict__ kn,   // [B][NT][D] bf16
    ushort* __restrict__ ap5,        // attn_it panels: [B][8][16][4096]
    ushort* __restrict__ ap7)        // attn_ti panels: [B][4][32][4096]
{
  __shared__ __align__(16) ushort Asm[2][64 * 32];     // 2 x 4KB
  __shared__ __align__(16) ushort Bsm[2][512 * 32];    // 2 x 32KB
  __shared__ __align__(16) float redm[64][8];
  __shared__ __align__(16) float reds[64][8];

  const int bid = blockIdx.x;
  const int sid = (bid & 7) * 64 + (bid >> 3);
  const int b   = sid >> 4;            // batch
  const int i0  = (sid & 15) * 64;     // i-block base
  const int tid  = threadIdx.x;
  const int w    = tid >> 6;           // wave 0..7 -> t-range w*64
  const int lane = tid & 63;
  const int lr   = lane & 15;
  const int g    = lane >> 4;

  const ushort* qb = qn + ((size_t)b * NI_ + i0) * D_;
  const ushort* kb = kn + (size_t)b * NT_ * D_;

  const int srow = tid >> 2;
  const int scol = (tid & 3) * 8;
  const int wp = (((tid >> 6) << 6) | (((tid >> 2) & 15) << 2)
                | ((tid & 3) ^ ((tid >> 3) & 3))) * 8;
  const int chunkLane = ((lane & 15) << 2) | ((lane >> 4) ^ ((lane >> 1) & 3));

  uint4 ra, rb0, rb1, rb2, rb3;
  auto LOAD = [&](int t) {
    const int ko = t * 32 + scol;
    if (tid < 256) ra = *reinterpret_cast<const uint4*>(qb + (size_t)srow * D_ + ko);
    rb0 = *reinterpret_cast<const uint4*>(kb + (size_t)(srow      ) * D_ + ko);
    rb1 = *reinterpret_cast<const uint4*>(kb + (size_t)(srow + 128) * D_ + ko);
    rb2 = *reinterpret_cast<const uint4*>(kb + (size_t)(srow + 256) * D_ + ko);
    rb3 = *reinterpret_cast<const uint4*>(kb + (size_t)(srow + 384) * D_ + ko);
  };
  auto WRITE = [&](int nb) {
    if (tid < 256) *reinterpret_cast<uint4*>(&Asm[nb][wp]) = ra;
    *reinterpret_cast<uint4*>(&Bsm[nb][wp        ]) = rb0;
    *reinterpret_cast<uint4*>(&Bsm[nb][wp +  4096]) = rb1;
    *reinterpret_cast<uint4*>(&Bsm[nb][wp +  8192]) = rb2;
    *reinterpret_cast<uint4*>(&Bsm[nb][wp + 12288]) = rb3;
  };

  f32x4 acc[4][4];
#pragma unroll
  for (int i = 0; i < 4; ++i)
#pragma unroll
    for (int j = 0; j < 4; ++j) acc[i][j] = (f32x4){0.f, 0.f, 0.f, 0.f};

  LOAD(0); WRITE(0); __syncthreads();
  const int nst = D_ / 32;   // 32
  int cur = 0;
  for (int t = 0; t < nst; ++t) {
    if (t + 1 < nst) LOAD(t + 1);
    const ushort* As = Asm[cur];
    const ushort* Bs = Bsm[cur];
    bf16x8 af[4], bf[4];
#pragma unroll
    for (int i = 0; i < 4; ++i)
      af[i] = *reinterpret_cast<const bf16x8*>(As + (i * 64 + chunkLane) * 8);
#pragma unroll
    for (int j = 0; j < 4; ++j)
      bf[j] = *reinterpret_cast<const bf16x8*>(Bs + ((w * 4 + j) * 64 + chunkLane) * 8);
#pragma unroll
    for (int i = 0; i < 4; ++i)
#pragma unroll
      for (int j = 0; j < 4; ++j)
        acc[i][j] = __builtin_amdgcn_mfma_f32_16x16x32_bf16(af[i], bf[j], acc[i][j], 0, 0, 0);
    __syncthreads();
    if (t + 1 < nst) WRITE(cur ^ 1);
    __syncthreads();
    cur ^= 1;
  }

  // ---- softmax over full t (512) per i-row ----
  // C/D: row(i) = i*16 + g*4 + r, col(t) = w*64 + j*16 + lr
  const float c1 = 0.03125f * 1.44269504f;  // scale * log2(e)

  float mx[4][4];
#pragma unroll
  for (int i = 0; i < 4; ++i)
#pragma unroll
    for (int r = 0; r < 4; ++r) {
      float m = fmaxf(fmaxf(acc[i][0][r], acc[i][1][r]),
                      fmaxf(acc[i][2][r], acc[i][3][r]));
      m = fmaxf(m, __shfl_xor(m, 1));
      m = fmaxf(m, __shfl_xor(m, 2));
      m = fmaxf(m, __shfl_xor(m, 4));
      m = fmaxf(m, __shfl_xor(m, 8));
      mx[i][r] = m;
    }
  if (lr == 0) {
#pragma unroll
    for (int i = 0; i < 4; ++i)
#pragma unroll
      for (int r = 0; r < 4; ++r) redm[i * 16 + g * 4 + r][w] = mx[i][r];
  }
  __syncthreads();
  float gm[4][4];
#pragma unroll
  for (int i = 0; i < 4; ++i)
#pragma unroll
    for (int r = 0; r < 4; ++r) {
      const int row = i * 16 + g * 4 + r;
      const float4 a0 = *reinterpret_cast<const float4*>(&redm[row][0]);
      const float4 a1 = *reinterpret_cast<const float4*>(&redm[row][4]);
      gm[i][r] = fmaxf(fmaxf(fmaxf(a0.x, a0.y), fmaxf(a0.z, a0.w)),
                       fmaxf(fmaxf(a1.x, a1.y), fmaxf(a1.z, a1.w)));
    }

  float sm[4][4];
#pragma unroll
  for (int i = 0; i < 4; ++i)
#pragma unroll
    for (int r = 0; r < 4; ++r) sm[i][r] = 0.f;
#pragma unroll
  for (int i = 0; i < 4; ++i)
#pragma unroll
    for (int j = 0; j < 4; ++j)
#pragma unroll
      for (int r = 0; r < 4; ++r) {
        const float p = exp2f((acc[i][j][r] - gm[i][r]) * c1);
        acc[i][j][r] = p;
        sm[i][r] += p;
      }
#pragma unroll
  for (int i = 0; i < 4; ++i)
#pragma unroll
    for (int r = 0; r < 4; ++r) {
      float s = sm[i][r];
      s += __shfl_xor(s, 1);
      s += __shfl_xor(s, 2);
      s += __shfl_xor(s, 4);
      s += __shfl_xor(s, 8);
      sm[i][r] = s;
    }
  if (lr == 0) {
#pragma unroll
    for (int i = 0; i < 4; ++i)
#pragma unroll
      for (int r = 0; r < 4; ++r) reds[i * 16 + g * 4 + r][w] = sm[i][r];
  }
  __syncthreads();
  float inv[4][4];
#pragma unroll
  for (int i = 0; i < 4; ++i)
#pragma unroll
    for (int r = 0; r < 4; ++r) {
      const int row = i * 16 + g * 4 + r;
      const float4 a0 = *reinterpret_cast<const float4*>(&reds[row][0]);
      const float4 a1 = *reinterpret_cast<const float4*>(&reds[row][4]);
      inv[i][r] = 1.f / (a0.x + a0.y + a0.z + a0.w + a1.x + a1.y + a1.z + a1.w);
    }

  // ---- write attn to both A-panels ----
  const int mt5 = i0 >> 7;                 // attn_it M-tile (const per block)
#pragma unroll
  for (int i = 0; i < 4; ++i) {
    const int rbase = i0 + i * 16 + g * 4;           // global i of pk.x
    const int R5hi  = ((i0 >> 6) & 1) * 4 + i;       // (R>>4) in attn_it tile
    const int ks7   = rbase >> 5;                    // attn_ti k-step
    const int kc7   = (rbase >> 3) & 3;
    const int el7   = rbase & 7;                     // 0 or 4
#pragma unroll
    for (int j = 0; j < 4; ++j) {
      const int tcol = w * 64 + j * 16 + lr;
      ushort4 pk;
      pk.x = f2b(acc[i][j][0] * inv[i][0]);
      pk.y = f2b(acc[i][j][1] * inv[i][1]);
      pk.z = f2b(acc[i][j][2] * inv[i][2]);
      pk.w = f2b(acc[i][j][3] * inv[i][3]);
      // attn_ti panel: row-dim = t, k = i; 4 consecutive k-elems = 8B store
      const size_t tb7 = ((size_t)(b * 4 + (tcol >> 7)) * 32 + ks7) * 4096;
      const int c7 = (((tcol & 127) >> 4) << 6) | (kc7 << 4) | lr;
      *reinterpret_cast<ushort4*>(ap7 + tb7 + c7 * 8 + el7) = pk;
      // attn_it panel: row-dim = i, k = t; 4 rows -> 4 chunks (16B apart)
      const size_t tb5 = ((size_t)(b * 8 + mt5) * 16 + (tcol >> 5)) * 4096;
      const int c5 = (R5hi << 6) | (((tcol >> 3) & 3) << 4) | (g * 4);
      ushort* p5 = ap5 + tb5 + (size_t)c5 * 8 + (tcol & 7);
      p5[0]  = pk.x;
      p5[8]  = pk.y;
      p5[16] = pk.z;
      p5[24] = pk.w;
    }
  }
}

// ---------------------------------------------------------------------------
// bt_gemm v8: operands are PANELS -> staging loads fully sequential.
// R7 schedule (reg-staged double-buffer, 2 barriers/K-step) unchanged.
// LDS identity layout (chunk c at position c): writes lane-linear 16B stride,
// frag reads lane-linear (conflict-free). BK=32, 128x128 tile, 4 waves 2x2.
// grid (N/128, M/128, B), block 256.
// ---------------------------------------------------------------------------
__global__ __launch_bounds__(256) void bt_gemm_add_kernel(
    const ushort* __restrict__ Apan, // [B][M/128][K/32][4096]
    const ushort* __restrict__ Bpan, // [B][N/128][K/32][4096]
    const float* __restrict__ add,   // [B][M][N] f32
    float* __restrict__ out,         // [B][M][N] f32
    int M, int N, int K)
{
  __shared__ __align__(16) ushort Asm[2][128 * 32];   // 2 x 8KB
  __shared__ __align__(16) ushort Bsm[2][128 * 32];   // 2 x 8KB

  const int b    = blockIdx.z;
  const int m0   = blockIdx.y * 128;
  const int n0   = blockIdx.x * 128;
  const int tid  = threadIdx.x;
  const int w    = tid >> 6;
  const int lane = tid & 63;
  const int lr   = lane & 15;
  const int g    = lane >> 4;
  const int nst  = K / 32;

  const ushort* Ab = Apan + ((size_t)(b * (M >> 7) + (m0 >> 7)) * nst) * 4096;
  const ushort* Bb = Bpan + ((size_t)(b * (N >> 7) + (n0 >> 7)) * nst) * 4096;

  uint4 ra0, ra1, rbx0, rbx1;
  auto LOAD = [&](int t) {
    const ushort* at = Ab + (size_t)t * 4096;
    const ushort* bt = Bb + (size_t)t * 4096;
    ra0  = *reinterpret_cast<const uint4*>(at + tid * 8);
    ra1  = *reinterpret_cast<const uint4*>(at + 2048 + tid * 8);
    rbx0 = *reinterpret_cast<const uint4*>(bt + tid * 8);
    rbx1 = *reinterpret_cast<const uint4*>(bt + 2048 + tid * 8);
  };
  auto WRITE = [&](int nb) {
    *reinterpret_cast<uint4*>(&Asm[nb][tid * 8       ]) = ra0;
    *reinterpret_cast<uint4*>(&Asm[nb][tid * 8 + 2048]) = ra1;
    *reinterpret_cast<uint4*>(&Bsm[nb][tid * 8       ]) = rbx0;
    *reinterpret_cast<uint4*>(&Bsm[nb][tid * 8 + 2048]) = rbx1;
  };

  f32x4 acc[4][4];
#pragma unroll
  for (int i = 0; i < 4; ++i)
#pragma unroll
    for (int j = 0; j < 4; ++j) acc[i][j] = (f32x4){0.f, 0.f, 0.f, 0.f};

  LOAD(0); WRITE(0); __syncthreads();
  int cur = 0;
  for (int t = 0; t < nst; ++t) {
    if (t + 1 < nst) LOAD(t + 1);
    const ushort* As = Asm[cur];
    const ushort* Bs = Bsm[cur];
    bf16x8 af[4], bf[4];
#pragma unroll
    for (int i = 0; i < 4; ++i)
      af[i] = *reinterpret_cast<const bf16x8*>(
          As + (((w >> 1) * 4 + i) * 64 + lane) * 8);
#pragma unroll
    for (int j = 0; j < 4; ++j)
      bf[j] = *reinterpret_cast<const bf16x8*>(
          Bs + (((w & 1) * 4 + j) * 64 + lane) * 8);
#pragma unroll
    for (int i = 0; i < 4; ++i)
#pragma unroll
      for (int j = 0; j < 4; ++j)
        acc[i][j] = __builtin_amdgcn_mfma_f32_16x16x32_bf16(af[i], bf[j], acc[i][j], 0, 0, 0);
    __syncthreads();
    if (t + 1 < nst) WRITE(cur ^ 1);
    __syncthreads();
    cur ^= 1;
  }

  const size_t ob = (size_t)b * M * N;
  const int rbase = m0 + (w >> 1) * 64 + g * 4;
#pragma unroll
  for (int i = 0; i < 4; ++i)
#pragma unroll
    for (int j = 0; j < 4; ++j) {
      const int c = n0 + (w & 1) * 64 + j * 16 + lr;
#pragma unroll
      for (int r = 0; r < 4; ++r) {
        const size_t idx = ob + (size_t)(rbase + i * 16 + r) * N + c;
        out[idx] = add[idx] + acc[i][j][r];
      }
    }
}

// ---------------------------------------------------------------------------
// Schedule (all intermediates in ws; 256MB <= observed ~768MB):
//   ws: [ap_it 32MB][ap_ti 32MB][txnT 32MB][imnT 64MB][txn 32MB][imn 64MB]
//   1. ln(imgf)->imn  2. ln(txtf)->txn  3. qk -> attn panels
//   4. transpose txn->txnT panels  5. gemm5 -> out0
//   6. transpose imn->imnT panels  7. gemm7 -> out1
// ---------------------------------------------------------------------------
extern "C" void kernel_launch(void* const* d_in, const int* in_sizes, int n_in,
                              void* d_out, int out_size, void* d_ws, size_t ws_size,
                              hipStream_t stream) {
  const float* imgf  = (const float*)d_in[0];
  const float* txtf  = (const float*)d_in[1];
  const float* gamma = (const float*)d_in[2];
  const float* beta  = (const float*)d_in[3];

  float* out0 = (float*)d_out;                       // [B][NI][D] f32
  float* out1 = out0 + (size_t)B_ * NI_ * D_;        // [B][NT][D] f32

  const size_t MB32 = (size_t)B_ * NT_ * NI_ * 2;    // 33,554,432 B
  char* ws = (char*)d_ws;
  ushort* ap_it = (ushort*)ws;                       // [B][8][16][4096] 32MB
  ushort* ap_ti = (ushort*)(ws +     MB32);          // [B][4][32][4096] 32MB
  ushort* txnT  = (ushort*)(ws + 2 * MB32);          // panels 32MB
  ushort* imnT  = (ushort*)(ws + 3 * MB32);          // panels 64MB
  ushort* txn   = (ushort*)(ws + 5 * MB32);          // [B][NT][D] 32MB
  ushort* imn   = (ushort*)(ws + 6 * MB32);          // [B][NI][D] 64MB

  // 1-2: layernorms -> bf16
  ln_bf16_kernel<<<(B_ * NI_) / 4, 256, 0, stream>>>(imgf, gamma, beta, imn);
  ln_bf16_kernel<<<(B_ * NT_) / 4, 256, 0, stream>>>(txtf, gamma, beta, txn);
  // 3: QK^T + softmax -> attn A-panels (512 blocks, XCD-swizzled)
  qk_softmax_kernel<<<(NI_ / 64) * B_, 512, 0, stream>>>(imn, txn, ap_it, ap_ti);
  // 4: text_norm -> B-panels for gemm5
  transpose_pan_kernel<<<dim3(D_ / 64, NT_ / 64, B_), 256, 0, stream>>>(txn, txnT, NT_, D_);
  // 5: out0 = image + attn @ text_norm
  bt_gemm_add_kernel<<<dim3(D_ / 128, NI_ / 128, B_), 256, 0, stream>>>(
      ap_it, txnT, imgf, out0, NI_, D_, NT_);
  // 6: image_norm -> B-panels for gemm7
  transpose_pan_kernel<<<dim3(D_ / 64, NI_ / 64, B_), 256, 0, stream>>>(imn, imnT, NI_, D_);
  // 7: out1 = text + attn^T @ image_norm
  bt_gemm_add_kernel<<<dim3(D_ / 128, NT_ / 128, B_), 256, 0, stream>>>(
      ap_ti, imnT, txtf, out1, NT_, D_, NI_);
}

// Round 11
// 320.007 us; speedup vs baseline: 1.1379x; 1.1226x over previous
//
#include <hip/hip_runtime.h>
#include <hip/hip_bf16.h>

// Problem constants
#define B_  32
#define NI_ 1024
#define NT_ 512
#define D_  1024

typedef __attribute__((ext_vector_type(8))) short bf16x8;   // 8 bf16 = 4 VGPRs
typedef __attribute__((ext_vector_type(4))) float f32x4;    // MFMA accumulator

// round-to-nearest-even f32 -> bf16 (values are finite here)
__device__ __forceinline__ ushort f2b(float f) {
  unsigned u = __builtin_bit_cast(unsigned, f);
  u = (u + 0x7FFFu + ((u >> 16) & 1u)) >> 16;
  return (ushort)u;
}

// ---------------------------------------------------------------------------
// LDS tile scheme (XOR-swizzled chunk order; bank-verified R6/R7):
//   A [rows][32] bf16 tile is 16-row blocks of 64 16B-chunks.
//   Staging thread t writes at wpos = ((t>>6)<<6) | (((t>>2)&15)<<2)
//     | ((t&3) ^ ((t>>3)&3)).
//   MFMA frag read lane l, block bi: chunk = bi*64 + chunkLane,
//     chunkLane = ((l&15)<<2) | ((l>>4) ^ ((l>>1)&3)).
//   Both ds_write_b128 and ds_read_b128 conflict-free.
// ---------------------------------------------------------------------------

// ---------------------------------------------------------------------------
// LayerNorm over D=1024, fp32 in -> bf16 out. One wave per row, 4 rows/block.
// ---------------------------------------------------------------------------
__global__ __launch_bounds__(256) void ln_bf16_kernel(
    const float* __restrict__ x, const float* __restrict__ gamma,
    const float* __restrict__ beta, ushort* __restrict__ out)
{
  const int row  = blockIdx.x * 4 + (threadIdx.x >> 6);
  const int lane = threadIdx.x & 63;
  const float* xr = x + (size_t)row * D_;
  float4 v[4];
  float s = 0.f, sq = 0.f;
#pragma unroll
  for (int q = 0; q < 4; ++q) {
    v[q] = *reinterpret_cast<const float4*>(xr + q * 256 + lane * 4);
    s  += v[q].x + v[q].y + v[q].z + v[q].w;
    sq += v[q].x*v[q].x + v[q].y*v[q].y + v[q].z*v[q].z + v[q].w*v[q].w;
  }
#pragma unroll
  for (int m = 1; m < 64; m <<= 1) {
    s  += __shfl_xor(s,  m);
    sq += __shfl_xor(sq, m);
  }
  const float mean = s * (1.f / D_);
  const float rstd = rsqrtf(sq * (1.f / D_) - mean * mean + 1e-5f);
  ushort* orow = out + (size_t)row * D_;
#pragma unroll
  for (int q = 0; q < 4; ++q) {
    const float4 g  = *reinterpret_cast<const float4*>(gamma + q * 256 + lane * 4);
    const float4 bt = *reinterpret_cast<const float4*>(beta  + q * 256 + lane * 4);
    ushort4 o;
    o.x = f2b((v[q].x - mean) * rstd * g.x + bt.x);
    o.y = f2b((v[q].y - mean) * rstd * g.y + bt.y);
    o.z = f2b((v[q].z - mean) * rstd * g.z + bt.z);
    o.w = f2b((v[q].w - mean) * rstd * g.w + bt.w);
    *reinterpret_cast<ushort4*>(orow + q * 256 + lane * 4) = o;
  }
}

// ---------------------------------------------------------------------------
// bf16 transpose [R][C] -> [C][R], per batch. 64x64 LDS tile.
// grid (C/64, R/64, B), block 256.
// ---------------------------------------------------------------------------
__global__ __launch_bounds__(256) void transpose_bf16_kernel(
    const ushort* __restrict__ in, ushort* __restrict__ out, int R, int C)
{
  __shared__ ushort lds[64][68];
  const size_t nb = (size_t)blockIdx.z * (size_t)R * C;
  const ushort* ib = in + nb;
  ushort* ob = out + nb;
  const int c0 = blockIdx.x * 64, r0 = blockIdx.y * 64;
  const int t = threadIdx.x;
#pragma unroll
  for (int it = 0; it < 2; ++it) {
    const int r = (t >> 3) + 32 * it;
    const int c = (t & 7) * 8;
    uint4 val = *reinterpret_cast<const uint4*>(ib + (size_t)(r0 + r) * C + c0 + c);
    *reinterpret_cast<uint2*>(&lds[r][c])     = make_uint2(val.x, val.y);
    *reinterpret_cast<uint2*>(&lds[r][c + 4]) = make_uint2(val.z, val.w);
  }
  __syncthreads();
#pragma unroll
  for (int it = 0; it < 2; ++it) {
    const int c  = (t >> 3) + 32 * it;  // output row = original col
    const int rb = (t & 7) * 8;         // original row chunk
    union { ushort u[8]; uint4 v; } pk;
#pragma unroll
    for (int j = 0; j < 8; ++j) pk.u[j] = lds[rb + j][c];
    *reinterpret_cast<uint4*>(ob + (size_t)(c0 + c) * R + r0 + rb) = pk.v;
  }
}

// ---------------------------------------------------------------------------
// qk_softmax v9: R7 structure (reg-staged dbuf, XOR-swizzled LDS); softmax
// WITHOUT max-subtraction (|S|=|dot/32| <~ 10 for LN'd inputs -> exp safe in
// f32; algebraically identical). Removes the mx reduce + 1 LDS round trip +
// 1 barrier. Block = 64 i x 512 t, 8 waves. Grid 512, XCD-swizzled.
// ---------------------------------------------------------------------------
__global__ __launch_bounds__(512) void qk_softmax_kernel(
    const ushort* __restrict__ qn,   // [B][NI][D] bf16
    const ushort* __restrict__ kn,   // [B][NT][D] bf16
    ushort* __restrict__ attn_it,    // [B][NI][NT] bf16
    ushort* __restrict__ attn_ti)    // [B][NT][NI] bf16
{
  __shared__ __align__(16) ushort Asm[2][64 * 32];     // 2 x 4KB
  __shared__ __align__(16) ushort Bsm[2][512 * 32];    // 2 x 32KB
  __shared__ __align__(16) float reds[64][8];

  // bijective XCD swizzle (512 blocks, 64 per XCD = 4 consecutive batches)
  const int bid = blockIdx.x;
  const int sid = (bid & 7) * 64 + (bid >> 3);
  const int b   = sid >> 4;            // batch
  const int i0  = (sid & 15) * 64;     // i-block base
  const int tid  = threadIdx.x;
  const int w    = tid >> 6;           // wave 0..7 -> t-range w*64
  const int lane = tid & 63;
  const int lr   = lane & 15;
  const int g    = lane >> 4;

  const ushort* qb = qn + ((size_t)b * NI_ + i0) * D_;
  const ushort* kb = kn + (size_t)b * NT_ * D_;

  const int srow = tid >> 2;
  const int scol = (tid & 3) * 8;
  const int wp = (((tid >> 6) << 6) | (((tid >> 2) & 15) << 2)
                | ((tid & 3) ^ ((tid >> 3) & 3))) * 8;
  const int chunkLane = ((lane & 15) << 2) | ((lane >> 4) ^ ((lane >> 1) & 3));

  uint4 ra, rb0, rb1, rb2, rb3;
  auto LOAD = [&](int t) {
    const int ko = t * 32 + scol;
    if (tid < 256) ra = *reinterpret_cast<const uint4*>(qb + (size_t)srow * D_ + ko);
    rb0 = *reinterpret_cast<const uint4*>(kb + (size_t)(srow      ) * D_ + ko);
    rb1 = *reinterpret_cast<const uint4*>(kb + (size_t)(srow + 128) * D_ + ko);
    rb2 = *reinterpret_cast<const uint4*>(kb + (size_t)(srow + 256) * D_ + ko);
    rb3 = *reinterpret_cast<const uint4*>(kb + (size_t)(srow + 384) * D_ + ko);
  };
  auto WRITE = [&](int nb) {
    if (tid < 256) *reinterpret_cast<uint4*>(&Asm[nb][wp]) = ra;
    *reinterpret_cast<uint4*>(&Bsm[nb][wp        ]) = rb0;
    *reinterpret_cast<uint4*>(&Bsm[nb][wp +  4096]) = rb1;
    *reinterpret_cast<uint4*>(&Bsm[nb][wp +  8192]) = rb2;
    *reinterpret_cast<uint4*>(&Bsm[nb][wp + 12288]) = rb3;
  };

  f32x4 acc[4][4];
#pragma unroll
  for (int i = 0; i < 4; ++i)
#pragma unroll
    for (int j = 0; j < 4; ++j) acc[i][j] = (f32x4){0.f, 0.f, 0.f, 0.f};

  LOAD(0); WRITE(0); __syncthreads();
  const int nst = D_ / 32;   // 32
  int cur = 0;
  for (int t = 0; t < nst; ++t) {
    if (t + 1 < nst) LOAD(t + 1);
    const ushort* As = Asm[cur];
    const ushort* Bs = Bsm[cur];
    bf16x8 af[4], bf[4];
#pragma unroll
    for (int i = 0; i < 4; ++i)
      af[i] = *reinterpret_cast<const bf16x8*>(As + (i * 64 + chunkLane) * 8);
#pragma unroll
    for (int j = 0; j < 4; ++j)
      bf[j] = *reinterpret_cast<const bf16x8*>(Bs + ((w * 4 + j) * 64 + chunkLane) * 8);
#pragma unroll
    for (int i = 0; i < 4; ++i)
#pragma unroll
      for (int j = 0; j < 4; ++j)
        acc[i][j] = __builtin_amdgcn_mfma_f32_16x16x32_bf16(af[i], bf[j], acc[i][j], 0, 0, 0);
    __syncthreads();
    if (t + 1 < nst) WRITE(cur ^ 1);
    __syncthreads();
    cur ^= 1;
  }

  // ---- softmax over full t (512) per i-row, no max-shift ----
  // C/D: row(i) = i*16 + g*4 + r, col(t) = w*64 + j*16 + lr
  const float c1 = 0.03125f * 1.44269504f;  // scale * log2(e)

  float sm[4][4];
#pragma unroll
  for (int i = 0; i < 4; ++i)
#pragma unroll
    for (int r = 0; r < 4; ++r) sm[i][r] = 0.f;
#pragma unroll
  for (int i = 0; i < 4; ++i)
#pragma unroll
    for (int j = 0; j < 4; ++j)
#pragma unroll
      for (int r = 0; r < 4; ++r) {
        const float p = exp2f(acc[i][j][r] * c1);
        acc[i][j][r] = p;
        sm[i][r] += p;
      }
#pragma unroll
  for (int i = 0; i < 4; ++i)
#pragma unroll
    for (int r = 0; r < 4; ++r) {
      float s = sm[i][r];
      s += __shfl_xor(s, 1);
      s += __shfl_xor(s, 2);
      s += __shfl_xor(s, 4);
      s += __shfl_xor(s, 8);
      sm[i][r] = s;
    }
  if (lr == 0) {
#pragma unroll
    for (int i = 0; i < 4; ++i)
#pragma unroll
      for (int r = 0; r < 4; ++r) reds[i * 16 + g * 4 + r][w] = sm[i][r];
  }
  __syncthreads();
  float inv[4][4];
#pragma unroll
  for (int i = 0; i < 4; ++i)
#pragma unroll
    for (int r = 0; r < 4; ++r) {
      const int row = i * 16 + g * 4 + r;
      const float4 a0 = *reinterpret_cast<const float4*>(&reds[row][0]);
      const float4 a1 = *reinterpret_cast<const float4*>(&reds[row][4]);
      inv[i][r] = 1.f / (a0.x + a0.y + a0.z + a0.w + a1.x + a1.y + a1.z + a1.w);
    }

  // ---- write attn in both layouts ----
#pragma unroll
  for (int i = 0; i < 4; ++i) {
    const int rbase = i0 + i * 16 + g * 4;
#pragma unroll
    for (int j = 0; j < 4; ++j) {
      const int tcol = w * 64 + j * 16 + lr;
      ushort4 pk;
      pk.x = f2b(acc[i][j][0] * inv[i][0]);
      pk.y = f2b(acc[i][j][1] * inv[i][1]);
      pk.z = f2b(acc[i][j][2] * inv[i][2]);
      pk.w = f2b(acc[i][j][3] * inv[i][3]);
      ushort* it_p = attn_it + ((size_t)b * NI_ + rbase) * NT_ + tcol;
      it_p[0 * NT_] = pk.x;
      it_p[1 * NT_] = pk.y;
      it_p[2 * NT_] = pk.z;
      it_p[3 * NT_] = pk.w;
      *reinterpret_cast<ushort4*>(attn_ti + ((size_t)b * NT_ + tcol) * NI_ + rbase) = pk;
    }
  }
}

// ---------------------------------------------------------------------------
// bt_gemm v9: R7 schedule (reg-staged double-buffer, XOR-swizzled LDS),
// 1D grid with bijective CHUNKED XCD swizzle: each XCD gets a contiguous
// run of (x,y,z) tiles (~1 batch) so A/B panel re-reads hit the local L2.
// C[m][n] = add[m][n] + sum_k A[m][k]*Bm[n][k]. BK=32, 128x128, 4 waves.
// grid 1D = (N/128)*(M/128)*B (divisible by 8), block 256.
// ---------------------------------------------------------------------------
__global__ __launch_bounds__(256) void bt_gemm_add_kernel(
    const ushort* __restrict__ A,   // [B][M][K] bf16
    const ushort* __restrict__ Bm,  // [B][N][K] bf16
    const float* __restrict__ add,  // [B][M][N] f32
    float* __restrict__ out,        // [B][M][N] f32
    int M, int N, int K)
{
  __shared__ __align__(16) ushort Asm[2][128 * 32];   // 2 x 8KB
  __shared__ __align__(16) ushort Bsm[2][128 * 32];   // 2 x 8KB

  const int nwx = N >> 7, nwy = M >> 7;
  const int per = (nwx * nwy * B_) >> 3;         // blocks per XCD
  const int sid = (blockIdx.x & 7) * per + (blockIdx.x >> 3);
  const int b   = sid / (nwx * nwy);
  const int rem = sid - b * (nwx * nwy);
  const int m0  = (rem / nwx) * 128;
  const int n0  = (rem % nwx) * 128;

  const int tid  = threadIdx.x;
  const int w    = tid >> 6;
  const int lane = tid & 63;
  const int lr   = lane & 15;
  const int g    = lane >> 4;

  const ushort* Ab = A  + ((size_t)b * M + m0) * K;
  const ushort* Bb = Bm + ((size_t)b * N + n0) * K;

  const int srow = tid >> 2;           // 0..63
  const int scol = (tid & 3) * 8;
  const int wp = (((tid >> 6) << 6) | (((tid >> 2) & 15) << 2)
                | ((tid & 3) ^ ((tid >> 3) & 3))) * 8;
  const int chunkLane = ((lane & 15) << 2) | ((lane >> 4) ^ ((lane >> 1) & 3));

  uint4 ra0, ra1, rbx0, rbx1;
  auto LOAD = [&](int t) {
    const int ko = t * 32 + scol;
    ra0  = *reinterpret_cast<const uint4*>(Ab + (size_t)(srow     ) * K + ko);
    ra1  = *reinterpret_cast<const uint4*>(Ab + (size_t)(srow + 64) * K + ko);
    rbx0 = *reinterpret_cast<const uint4*>(Bb + (size_t)(srow     ) * K + ko);
    rbx1 = *reinterpret_cast<const uint4*>(Bb + (size_t)(srow + 64) * K + ko);
  };
  auto WRITE = [&](int nb) {
    *reinterpret_cast<uint4*>(&Asm[nb][wp       ]) = ra0;
    *reinterpret_cast<uint4*>(&Asm[nb][wp + 2048]) = ra1;
    *reinterpret_cast<uint4*>(&Bsm[nb][wp       ]) = rbx0;
    *reinterpret_cast<uint4*>(&Bsm[nb][wp + 2048]) = rbx1;
  };

  f32x4 acc[4][4];
#pragma unroll
  for (int i = 0; i < 4; ++i)
#pragma unroll
    for (int j = 0; j < 4; ++j) acc[i][j] = (f32x4){0.f, 0.f, 0.f, 0.f};

  LOAD(0); WRITE(0); __syncthreads();
  const int nst = K / 32;
  int cur = 0;
  for (int t = 0; t < nst; ++t) {
    if (t + 1 < nst) LOAD(t + 1);
    const ushort* As = Asm[cur];
    const ushort* Bs = Bsm[cur];
    bf16x8 af[4], bf[4];
#pragma unroll
    for (int i = 0; i < 4; ++i)
      af[i] = *reinterpret_cast<const bf16x8*>(
          As + (((w >> 1) * 4 + i) * 64 + chunkLane) * 8);
#pragma unroll
    for (int j = 0; j < 4; ++j)
      bf[j] = *reinterpret_cast<const bf16x8*>(
          Bs + (((w & 1) * 4 + j) * 64 + chunkLane) * 8);
#pragma unroll
    for (int i = 0; i < 4; ++i)
#pragma unroll
      for (int j = 0; j < 4; ++j)
        acc[i][j] = __builtin_amdgcn_mfma_f32_16x16x32_bf16(af[i], bf[j], acc[i][j], 0, 0, 0);
    __syncthreads();
    if (t + 1 < nst) WRITE(cur ^ 1);
    __syncthreads();
    cur ^= 1;
  }

  const size_t ob = (size_t)b * M * N;
  const int rbase = m0 + (w >> 1) * 64 + g * 4;
#pragma unroll
  for (int i = 0; i < 4; ++i)
#pragma unroll
    for (int j = 0; j < 4; ++j) {
      const int c = n0 + (w & 1) * 64 + j * 16 + lr;
#pragma unroll
      for (int r = 0; r < 4; ++r) {
        const size_t idx = ob + (size_t)(rbase + i * 16 + r) * N + c;
        out[idx] = add[idx] + acc[i][j][r];
      }
    }
}

// ---------------------------------------------------------------------------
// Schedule (buffer aliasing; ws_size >= 96 MB, observed ~768MB):
//   imn in out1 region, txn in out0 region (dead before outputs written);
//   ws: [attn_ti][attn_it][txnT]; imnT reuses attn_it+txnT after GEMM5.
// ---------------------------------------------------------------------------
extern "C" void kernel_launch(void* const* d_in, const int* in_sizes, int n_in,
                              void* d_out, int out_size, void* d_ws, size_t ws_size,
                              hipStream_t stream) {
  const float* imgf  = (const float*)d_in[0];
  const float* txtf  = (const float*)d_in[1];
  const float* gamma = (const float*)d_in[2];
  const float* beta  = (const float*)d_in[3];

  float* out0 = (float*)d_out;                       // [B][NI][D] f32
  float* out1 = out0 + (size_t)B_ * NI_ * D_;        // [B][NT][D] f32

  const size_t SZ = (size_t)B_ * NT_ * NI_ * 2;      // 33,554,432 B
  char* ws = (char*)d_ws;
  ushort* attn_ti = (ushort*)ws;                     // [B][NT][NI]
  ushort* attn_it = (ushort*)(ws + SZ);              // [B][NI][NT]
  ushort* txnT    = (ushort*)(ws + 2 * SZ);          // [B][D][NT]
  ushort* imnT    = (ushort*)(ws + SZ);              // [B][D][NI] (aliases attn_it+txnT)
  ushort* imn     = (ushort*)out1;                   // [B][NI][D] bf16 (scratch in out1)
  ushort* txn     = (ushort*)out0;                   // [B][NT][D] bf16 (scratch in out0)

  // 1-2: layernorms -> bf16
  ln_bf16_kernel<<<(B_ * NI_) / 4, 256, 0, stream>>>(imgf, gamma, beta, imn);
  ln_bf16_kernel<<<(B_ * NT_) / 4, 256, 0, stream>>>(txtf, gamma, beta, txn);
  // 3: QK^T + softmax -> attn in both layouts (512 blocks, XCD-swizzled)
  qk_softmax_kernel<<<(NI_ / 64) * B_, 512, 0, stream>>>(imn, txn, attn_it, attn_ti);
  // 4: text_norm^T
  transpose_bf16_kernel<<<dim3(D_ / 64, NT_ / 64, B_), 256, 0, stream>>>(txn, txnT, NT_, D_);
  // 5: out0 = image + attn @ text_norm   (overwrites txn scratch — dead)
  bt_gemm_add_kernel<<<(D_ / 128) * (NI_ / 128) * B_, 256, 0, stream>>>(
      attn_it, txnT, imgf, out0, NI_, D_, NT_);
  // 6: image_norm^T (overwrites attn_it + txnT — dead)
  transpose_bf16_kernel<<<dim3(D_ / 64, NI_ / 64, B_), 256, 0, stream>>>(imn, imnT, NI_, D_);
  // 7: out1 = text + attn^T @ image_norm (overwrites imn scratch — dead)
  bt_gemm_add_kernel<<<(D_ / 128) * (NT_ / 128) * B_, 256, 0, stream>>>(
      attn_ti, imnT, txtf, out1, NT_, D_, NI_);
}